// Round 13
// baseline (61.130 us; speedup 1.0000x reference)
//
#include <hip/hip_runtime.h>

#define N_NODES 10000
#define FEATS 32
#define HEADS 4
#define SAMPLES 256
#define N_BATCH 2048
#define NGROUP 40                       // ceil(N_NODES / 256)
#define NWORDS (NGROUP * 4)             // 160 u64 words per mask row

typedef float f32x4 __attribute__((ext_vector_type(4)));
typedef _Float16 f16x8 __attribute__((ext_vector_type(8)));
typedef unsigned long long u64;

// ws layout:
//   [0)          u64 mask_table[N_NODES][NWORDS]   12,800,000 B
//   [12800000)   _Float16 pos16[H][N_NODES][FEATS]  2,560,000 B
#define WS_P16_OFF  12800000
#define WS_NEED_V2  15360000
#define WS_NEED_V1  12800000
#define POS_ELEMS   (HEADS * N_NODES * FEATS)   // 1,280,000

// ======= Kernel 1: per-NODE mask dedup + pos->fp16 conversion ==============
// Blocks [0,4096): endpoint v = edge_flat[bid]; first occurrence streams
//   edge_mat row v (40 KB, MLP-10 batched) -> sign bitmask in mask_table[v].
//   Duplicates exit after an L2-resident scan of edge_flat[0..bid).
// Blocks [4096,4736): convert pos (fp32) -> ws_pos16 (fp16), 2048 elems/blk.
//   (Writes exactly the table k2 gathers from -> warms L2 with useful data.)
// Blocks < N_BATCH also zero out[] for k2's atomic accumulate.
__global__ __launch_bounds__(256) void mask_dedup_kernel(
    const int* __restrict__ edge,        // flat (N_BATCH*2)
    const float* __restrict__ edge_mat,
    const float* __restrict__ pos,
    u64* __restrict__ mask_table,
    _Float16* __restrict__ ws_pos16,
    float* __restrict__ out,
    int do_conv)
{
    const int bid  = blockIdx.x;
    const int tid  = threadIdx.x;
    const int w    = tid >> 6;
    const int lane = tid & 63;

    if (bid >= 2 * N_BATCH) {
        // ---- conversion role ----
        if (!do_conv) return;
        const int idx = (bid - 2 * N_BATCH) * 2048 + tid * 8;
        if (idx < POS_ELEMS) {
            const float4 v0 = *(const float4*)(pos + idx);
            const float4 v1 = *(const float4*)(pos + idx + 4);
            f16x8 o;
            o[0] = (_Float16)v0.x; o[1] = (_Float16)v0.y;
            o[2] = (_Float16)v0.z; o[3] = (_Float16)v0.w;
            o[4] = (_Float16)v1.x; o[5] = (_Float16)v1.y;
            o[6] = (_Float16)v1.z; o[7] = (_Float16)v1.w;
            *(f16x8*)(ws_pos16 + idx) = o;
        }
        return;
    }

    if (tid == 0 && bid < N_BATCH) out[bid] = 0.f;

    const int v = edge[bid];

    // Duplicate scan over earlier endpoints (16 KB, L2-resident).
    __shared__ int s_dup;
    if (tid == 0) s_dup = 0;
    __syncthreads();
    for (int j = tid; j < bid; j += 256)
        if (edge[j] == v) s_dup = 1;
    __syncthreads();
    if (s_dup) return;

    const float* rp = edge_mat + (size_t)v * N_NODES;
    u64* wsn = mask_table + (size_t)v * NWORDS;

    // Batch phase: all 10 x 1 KB loads in flight before any ballot.
    f32x4 val[10];
    #pragma unroll
    for (int i = 0; i < 10; ++i) {
        const int base = (i * 4 + w) * 256 + lane * 4;
        f32x4 t = {-1.f, -1.f, -1.f, -1.f};
        if (base < N_NODES) t = *(const f32x4*)(rp + base);
        val[i] = t;
    }
    // Ballot phase.
    #pragma unroll
    for (int i = 0; i < 10; ++i) {
        const int g = i * 4 + w;
        u64 b0 = __ballot(val[i].x > 0.f);
        u64 b1 = __ballot(val[i].y > 0.f);
        u64 b2 = __ballot(val[i].z > 0.f);
        u64 b3 = __ballot(val[i].w > 0.f);
        if (lane < 4) {
            u64 bb = lane == 0 ? b0 : lane == 1 ? b1 : lane == 2 ? b2 : b3;
            wsn[g * 4 + lane] = bb;
        }
    }
}

// ======= Kernel 2 (v2): fp16 register-direct gather ========================
// Block b: head h = b & 3; wave w handles edge n = (b>>2) + 512w. Round-robin
// XCD (b % 8) => XCD x only touches pos16[x & 3] (0.64 MB, L2-resident).
// fp16 row = 64 B; 4 lanes/row, lane q loads ONE 16 B vector (feats 8q..8q+7)
// -> each gather instr covers 16 rows x 16 B. TWO chunks' loads (8) batched
// before consumption (MLP depth 8). Anchors/field fp32 (exact); 2-level
// shfl_xor butterfly; em/exp/acc redundant per lane (4x, folded via den+32).
__global__ __launch_bounds__(256, 4) void madgraph_v2(
    const int* __restrict__ edge,
    const int* __restrict__ mid0,
    const int* __restrict__ mid1,
    const float* __restrict__ pos,
    const float* __restrict__ field,
    const float* __restrict__ unc,
    const u64* __restrict__ mask_table,
    const _Float16* __restrict__ ws_pos16,
    float* __restrict__ out)
{
    const int b    = blockIdx.x;
    const int h    = b & 3;
    const int tid  = threadIdx.x;
    const int w    = tid >> 6;
    const int lane = tid & 63;
    const int n    = (b >> 2) + 512 * w;

    __shared__ u64 s_mask[4][2 * NWORDS];   // [w][0..159]=dst row, [160..)=src

    const int src = edge[2 * n];
    const int dst = edge[2 * n + 1];
    const float U = unc[0];

    const u64* wdst = mask_table + (size_t)dst * NWORDS;  // side0 (symmetry)
    const u64* wsrc = mask_table + (size_t)src * NWORDS;  // side1
    #pragma unroll
    for (int k = 0; k < 5; ++k) {
        const int idx = k * 64 + lane;
        s_mask[w][idx] = (idx < NWORDS) ? wdst[idx] : wsrc[idx - NWORDS];
    }

    const float*    posh   = pos      + (size_t)h * N_NODES * FEATS;
    const float*    fieldh = field    + (size_t)h * N_NODES * FEATS;
    const _Float16* p16h   = ws_pos16 + (size_t)h * N_NODES * FEATS;

    const int q = lane & 3;    // lane's 8-feat slice: feats [8q, 8q+8)
    const int g = lane >> 2;   // row-group index within 16

    // Anchor/field slices for both sides (8 float4 = 32 VGPRs), fp32 exact.
    float4 A[2][2], F[2][2];
    #pragma unroll
    for (int sd = 0; sd < 2; ++sd) {
        const float4* pa = (const float4*)(posh   + (size_t)(sd ? dst : src) * FEATS) + q * 2;
        const float4* pf = (const float4*)(fieldh + (size_t)(sd ? src : dst) * FEATS) + q * 2;
        A[sd][0] = pa[0]; A[sd][1] = pa[1];
        F[sd][0] = pf[0]; F[sd][1] = pf[1];
    }

    const size_t sb = ((size_t)h * N_BATCH + n) * SAMPLES;
    int mm[8];
    #pragma unroll
    for (int c = 0; c < 8; ++c)
        mm[c] = (c < 4 ? mid0 : mid1)[sb + (c & 3) * 64 + lane];

    float num = 0.f, den = 0.f;

    #pragma unroll
    for (int cc = 0; cc < 4; ++cc) {          // pair of chunks (2cc, 2cc+1)
        const int side = cc >> 1;             // uniform within the pair

        // Batch phase: all 8 gathers (2 chunks x 4 rows) issued up front.
        int   mA[8];
        f16x8 B[8];
        #pragma unroll
        for (int t = 0; t < 4; ++t) {
            mA[t]     = __shfl(mm[2 * cc],     t * 16 + g);
            mA[4 + t] = __shfl(mm[2 * cc + 1], t * 16 + g);
        }
        #pragma unroll
        for (int t = 0; t < 8; ++t)
            B[t] = *(const f16x8*)(p16h + (size_t)mA[t] * FEATS + q * 8);

        // Compute phase: 8 samples on batched registers.
        #pragma unroll
        for (int t = 0; t < 8; ++t) {
            float dh = 0.f, nh = 0.f;
            {
                float4 a = A[side][0], f = F[side][0];
                float dx = a.x - (float)B[t][0], dy = a.y - (float)B[t][1],
                      dz = a.z - (float)B[t][2], dw = a.w - (float)B[t][3];
                dh += dx * f.x + dy * f.y + dz * f.z + dw * f.w;
                nh += dx * dx + dy * dy + dz * dz + dw * dw;
            }
            {
                float4 a = A[side][1], f = F[side][1];
                float dx = a.x - (float)B[t][4], dy = a.y - (float)B[t][5],
                      dz = a.z - (float)B[t][6], dw = a.w - (float)B[t][7];
                dh += dx * f.x + dy * f.y + dz * f.z + dw * f.w;
                nh += dx * dx + dy * dy + dz * dz + dw * dw;
            }
            dh += __shfl_xor(dh, 1); nh += __shfl_xor(nh, 1);
            dh += __shfl_xor(dh, 2); nh += __shfl_xor(nh, 2);

            const u64 wbits =
                s_mask[w][side * NWORDS + ((mA[t] >> 8) << 2) + (mA[t] & 3)];
            const float em = ((wbits >> ((mA[t] >> 2) & 63)) & 1ull) ? U : -U;

            const float wgt = __expf(1.0f - sqrtf(nh));
            num += (dh + em) * wgt;   // each sample counted by 4 lanes
            den += wgt;
        }
    }

    #pragma unroll
    for (int off = 32; off > 0; off >>= 1) {
        num += __shfl_xor(num, off);
        den += __shfl_xor(den, off);
    }
    if (lane == 0) {
        // 4x-counted; sentinels add 8 true -> +32 scaled:
        // 0.25*(4N)/(4D+32) == 0.25*N/(D+8). k1 zeroed out[n] this launch.
        atomicAdd(out + n, 0.25f * (num / (den + 32.0f)));
    }
}

// ======= Kernel 2 (v1 fallback, R11 proven): fp32 gathers ==================
__global__ __launch_bounds__(256, 4) void madgraph_v1(
    const int* __restrict__ edge,
    const int* __restrict__ mid0,
    const int* __restrict__ mid1,
    const float* __restrict__ pos,
    const float* __restrict__ field,
    const float* __restrict__ unc,
    const u64* __restrict__ mask_table,
    float* __restrict__ out)
{
    const int b    = blockIdx.x;
    const int h    = b & 3;
    const int tid  = threadIdx.x;
    const int w    = tid >> 6;
    const int lane = tid & 63;
    const int n    = (b >> 2) + 512 * w;

    __shared__ u64 s_mask[4][2 * NWORDS];

    const int src = edge[2 * n];
    const int dst = edge[2 * n + 1];
    const float U = unc[0];

    const u64* wdst = mask_table + (size_t)dst * NWORDS;
    const u64* wsrc = mask_table + (size_t)src * NWORDS;
    #pragma unroll
    for (int k = 0; k < 5; ++k) {
        const int idx = k * 64 + lane;
        s_mask[w][idx] = (idx < NWORDS) ? wdst[idx] : wsrc[idx - NWORDS];
    }

    const float* posh   = pos   + (size_t)h * N_NODES * FEATS;
    const float* fieldh = field + (size_t)h * N_NODES * FEATS;
    const int q = lane & 3;
    const int g = lane >> 2;

    float4 A[2][2], F[2][2];
    #pragma unroll
    for (int sd = 0; sd < 2; ++sd) {
        const float4* pa = (const float4*)(posh   + (size_t)(sd ? dst : src) * FEATS);
        const float4* pf = (const float4*)(fieldh + (size_t)(sd ? src : dst) * FEATS);
        A[sd][0] = pa[q]; A[sd][1] = pa[q + 4];
        F[sd][0] = pf[q]; F[sd][1] = pf[q + 4];
    }

    const size_t sb = ((size_t)h * N_BATCH + n) * SAMPLES;
    int mm[8];
    #pragma unroll
    for (int c = 0; c < 8; ++c)
        mm[c] = (c < 4 ? mid0 : mid1)[sb + (c & 3) * 64 + lane];

    float num = 0.f, den = 0.f;
    #pragma unroll
    for (int c = 0; c < 8; ++c) {
        const int side = c >> 2;
        int    mArr[4];
        float4 B0[4], B1[4];
        #pragma unroll
        for (int t = 0; t < 4; ++t)
            mArr[t] = __shfl(mm[c], t * 16 + g);
        #pragma unroll
        for (int t = 0; t < 4; ++t) {
            const float4* rp = (const float4*)(posh + (size_t)mArr[t] * FEATS);
            B0[t] = rp[q];
            B1[t] = rp[q + 4];
        }
        #pragma unroll
        for (int t = 0; t < 4; ++t) {
            float dh = 0.f, nh = 0.f;
            {
                float4 a = A[side][0], f = F[side][0];
                float dx = a.x - B0[t].x, dy = a.y - B0[t].y,
                      dz = a.z - B0[t].z, dw = a.w - B0[t].w;
                dh += dx * f.x + dy * f.y + dz * f.z + dw * f.w;
                nh += dx * dx + dy * dy + dz * dz + dw * dw;
            }
            {
                float4 a = A[side][1], f = F[side][1];
                float dx = a.x - B1[t].x, dy = a.y - B1[t].y,
                      dz = a.z - B1[t].z, dw = a.w - B1[t].w;
                dh += dx * f.x + dy * f.y + dz * f.z + dw * f.w;
                nh += dx * dx + dy * dy + dz * dz + dw * dw;
            }
            dh += __shfl_xor(dh, 1); nh += __shfl_xor(nh, 1);
            dh += __shfl_xor(dh, 2); nh += __shfl_xor(nh, 2);
            const u64 wbits =
                s_mask[w][side * NWORDS + ((mArr[t] >> 8) << 2) + (mArr[t] & 3)];
            const float em = ((wbits >> ((mArr[t] >> 2) & 63)) & 1ull) ? U : -U;
            const float wgt = __expf(1.0f - sqrtf(nh));
            num += (dh + em) * wgt;
            den += wgt;
        }
    }
    #pragma unroll
    for (int off = 32; off > 0; off >>= 1) {
        num += __shfl_xor(num, off);
        den += __shfl_xor(den, off);
    }
    if (lane == 0)
        atomicAdd(out + n, 0.25f * (num / (den + 32.0f)));
}

extern "C" void kernel_launch(void* const* d_in, const int* in_sizes, int n_in,
                              void* d_out, int out_size, void* d_ws, size_t ws_size,
                              hipStream_t stream) {
    const int*   edge     = (const int*)  d_in[0];
    const int*   mid0     = (const int*)  d_in[1];
    const int*   mid1     = (const int*)  d_in[2];
    const float* pos      = (const float*)d_in[3];
    const float* field    = (const float*)d_in[4];
    const float* unc      = (const float*)d_in[5];
    const float* edge_mat = (const float*)d_in[6];
    float*       out      = (float*)d_out;

    u64*      mask_table = (u64*)d_ws;
    _Float16* ws_pos16   = (_Float16*)((char*)d_ws + WS_P16_OFF);
    const int v2 = ws_size >= (size_t)WS_NEED_V2;

    // 4096 mask/dedup blocks + 640 conversion blocks (conversion only if v2).
    mask_dedup_kernel<<<2 * N_BATCH + 640, 256, 0, stream>>>(
        edge, edge_mat, pos, mask_table, ws_pos16, out, v2);

    if (v2) {
        madgraph_v2<<<N_BATCH, 256, 0, stream>>>(edge, mid0, mid1, pos, field,
                                                 unc, mask_table, ws_pos16, out);
    } else {
        madgraph_v1<<<N_BATCH, 256, 0, stream>>>(edge, mid0, mid1, pos, field,
                                                 unc, mask_table, out);
    }
}